// Round 3
// baseline (587.453 us; speedup 1.0000x reference)
//
#include <hip/hip_runtime.h>

#define N_NODES 131072
#define MAXL 4096

// ws float offsets
#define OFF_QW     0u          // 64*256   folded (Q@WK)/16
#define OFF_QO     16384u      // 64*256   Q@WO^T
#define OFF_WF     32768u      // 256*256  WO@WV
#define OFF_QB     98304u      // 64
#define OFF_BVO    98368u      // 256
#define OFF_STARTS 98624u      // 65 ints
#define OFF_ASUM   98752u      // 64*64
#define OFF_A      102912u     // 131072*64
#define OFF_G      8491520u    // partial G slabs (or single G in atomic mode)

// ---------------- fused setup: Q/QW/QO/qb + Wf/bvo + starts ----------------
// blocks 0..63: cluster c = blockIdx -> Qrow in LDS, then fold
// blocks 64..319: i = blockIdx-64 -> Wf row
// block 320: starts binary search

__global__ __launch_bounds__(256) void k_setup(
    const float* __restrict__ Qp, const float* __restrict__ WQ_w,
    const float* __restrict__ WQ_b, const float* __restrict__ WK_w,
    const float* __restrict__ WK_b, const float* __restrict__ WV_w,
    const float* __restrict__ WV_b, const float* __restrict__ WO_w,
    const int* __restrict__ batch,
    float* __restrict__ QW, float* __restrict__ QO, float* __restrict__ qb,
    float* __restrict__ Wf, float* __restrict__ bvo, int* __restrict__ starts)
{
  __shared__ float Qrow[256];
  const int bb = blockIdx.x;
  const int d = threadIdx.x;

  if (bb < 64) {
    const int c = bb;
    // Q[c][d]
    float acc = WQ_b[d];
    #pragma unroll 4
    for (int k = 0; k < 256; k += 4) {
      float4 w = *(const float4*)&WQ_w[d * 256 + k];
      acc += Qp[c * 256 + k + 0] * w.x + Qp[c * 256 + k + 1] * w.y
           + Qp[c * 256 + k + 2] * w.z + Qp[c * 256 + k + 3] * w.w;
    }
    Qrow[d] = acc;
    __syncthreads();
    double aqw = 0.0;
    float aqo = 0.f;
    for (int j = 0; j < 256; ++j) {
      float qcj = Qrow[j];
      aqw += (double)qcj * (double)WK_w[j * 256 + d];   // coalesced over d
      aqo += qcj * WO_w[d * 256 + j];
    }
    QW[c * 256 + d] = (float)(aqw * 0.0625);  // 1/sqrt(256)
    QO[c * 256 + d] = aqo;
    if (d == 0) {
      double s = 0.0;
      for (int j = 0; j < 256; ++j) s += (double)Qrow[j] * (double)WK_b[j];
      qb[c] = (float)(s * 0.0625);
    }
  } else if (bb < 320) {
    const int i = bb - 64;
    float acc = 0.f;
    for (int j = 0; j < 256; ++j)
      acc += WO_w[i * 256 + j] * WV_w[j * 256 + d];     // coalesced over d
    Wf[i * 256 + d] = acc;
    if (d == 0) {
      float s = 0.f;
      for (int j = 0; j < 256; ++j) s += WV_b[j] * WO_w[i * 256 + j];
      bvo[i] = s;
    }
  } else {
    int t = d;
    if (t > 64) return;
    if (t == 0) { starts[0] = 0; return; }
    if (t == 64) { starts[64] = N_NODES; return; }
    int lo = 0, hi = N_NODES;
    while (lo < hi) {
      int mid = (lo + hi) >> 1;
      if (batch[mid] < t) lo = mid + 1; else hi = mid;
    }
    starts[t] = lo;
  }
}

// ---------------- pass 1: scores + softmax + argmax + mask ----------------
// 256-thread blocks, 64 nodes/block. Wave w handles clusters [16w,16w+16):
// thread = (node = t&63, cgroup = t>>6), acc[16] only -> no spills.
// qw pointer is wave-uniform -> scalar loads; x staged in LDS.

__global__ __launch_bounds__(256) void k_scores(
    const float* __restrict__ x, const int* __restrict__ batch,
    const float* __restrict__ qw, const float* __restrict__ qbv,
    const int* __restrict__ starts, float* __restrict__ A,
    float* __restrict__ out_arg, float* __restrict__ out_msk)
{
  __shared__ float xs[64 * 36];        // 64 nodes x 32 k, pad 36
  __shared__ float ss[64 * 65 + 128];  // scores + stats
  const int t = threadIdx.x;
  const int n0 = blockIdx.x * 64;
  const int node = t & 63;
  const int cg = t >> 6;               // 0..3, wave-uniform

  float acc[16];
  #pragma unroll
  for (int i = 0; i < 16; ++i) acc[i] = 0.f;

  #pragma unroll 1
  for (int kc = 0; kc < 8; ++kc) {
    const int k0 = kc * 32;
    // stage x[n0..n0+64) x [k0..k0+32): 512 float4, 2 per thread, coalesced
    #pragma unroll
    for (int u = 0; u < 2; ++u) {
      int v = t + 256 * u;
      int row = v >> 3, col = v & 7;
      *(float4*)&xs[row * 36 + col * 4] =
          *(const float4*)&x[(size_t)(n0 + row) * 256 + k0 + col * 4];
    }
    __syncthreads();
    #pragma unroll 1
    for (int h = 0; h < 2; ++h) {
      float4 xv0 = *(const float4*)&xs[node * 36 + h * 16 + 0];
      float4 xv1 = *(const float4*)&xs[node * 36 + h * 16 + 4];
      float4 xv2 = *(const float4*)&xs[node * 36 + h * 16 + 8];
      float4 xv3 = *(const float4*)&xs[node * 36 + h * 16 + 12];
      const float* qp = qw + (size_t)cg * 16 * 256 + k0 + h * 16;  // uniform
      #pragma unroll
      for (int i = 0; i < 16; ++i) {
        float4 q0 = *(const float4*)&qp[i * 256 + 0];
        float4 q1 = *(const float4*)&qp[i * 256 + 4];
        float4 q2 = *(const float4*)&qp[i * 256 + 8];
        float4 q3 = *(const float4*)&qp[i * 256 + 12];
        acc[i] += xv0.x * q0.x + xv0.y * q0.y + xv0.z * q0.z + xv0.w * q0.w
                + xv1.x * q1.x + xv1.y * q1.y + xv1.z * q1.z + xv1.w * q1.w
                + xv2.x * q2.x + xv2.y * q2.y + xv2.z * q2.z + xv2.w * q2.w
                + xv3.x * q3.x + xv3.y * q3.y + xv3.z * q3.z + xv3.w * q3.w;
      }
    }
    __syncthreads();
  }

  // scores -> LDS with bias
  #pragma unroll
  for (int i = 0; i < 16; ++i)
    ss[node * 65 + cg * 16 + i] = acc[i] + qbv[cg * 16 + i];
  __syncthreads();

  if (t < 64) {
    float m = ss[t * 65];
    int am = 0;
    for (int c = 1; c < 64; ++c) {
      float v = ss[t * 65 + c];
      if (v > m) { m = v; am = c; }     // strict > : first-max, matches np
    }
    float sum = 0.f;
    for (int c = 0; c < 64; ++c) sum += __expf(ss[t * 65 + c] - m);
    ss[64 * 65 + t] = 1.f / sum;
    ss[64 * 65 + 64 + t] = m;
    int n = n0 + t;
    int bg = batch[n];
    int pos = n - starts[bg];
    out_arg[(size_t)bg * MAXL + pos] = (float)am;
    out_msk[(size_t)bg * MAXL + pos] = 1.0f;
  }
  __syncthreads();

  // softmax weights A[n][c], coalesced float4
  {
    int nd = t >> 2, q = t & 3;
    float inv = ss[64 * 65 + nd], m = ss[64 * 65 + 64 + nd];
    #pragma unroll
    for (int u = 0; u < 4; ++u) {
      int c = q * 16 + u * 4;
      float4 v;
      v.x = __expf(ss[nd * 65 + c + 0] - m) * inv;
      v.y = __expf(ss[nd * 65 + c + 1] - m) * inv;
      v.z = __expf(ss[nd * 65 + c + 2] - m) * inv;
      v.w = __expf(ss[nd * 65 + c + 3] - m) * inv;
      *(float4*)&A[(size_t)(n0 + nd) * 64 + c] = v;
    }
  }
}

// ---------------- pass 2: G[b] = A_b^T X_b (8x8 register tile) ---------------

__global__ __launch_bounds__(256) void k_gacc(
    const float* __restrict__ x, const float* __restrict__ A,
    const int* __restrict__ starts, float* __restrict__ Gdst,
    float* __restrict__ asum, int use_atomic)
{
  __shared__ float as_[32 * 68];    // [n][c] pad 64->68
  __shared__ float xs[32 * 260];    // [n][d] pad 256->260
  const int t = threadIdx.x;
  const int b = blockIdx.y;
  const int s0 = starts[b], s1 = starts[b + 1];
  const int cg = t & 7, dg = t >> 3;   // c = cg*8+i, d = dg*8+j

  float acc[8][8];
  #pragma unroll
  for (int i = 0; i < 8; ++i)
    #pragma unroll
    for (int j = 0; j < 8; ++j) acc[i][j] = 0.f;
  float asv = 0.f;

  const int stride = gridDim.x * 32;
  for (int base = s0 + blockIdx.x * 32; base < s1; base += stride) {
    #pragma unroll
    for (int u = 0; u < 2; ++u) {
      int v = t + 256 * u;
      int row = v >> 4, col = v & 15;
      int gr = base + row;
      float4 av = make_float4(0.f, 0.f, 0.f, 0.f);
      if (gr < s1) av = *(const float4*)&A[(size_t)gr * 64 + col * 4];
      *(float4*)&as_[row * 68 + col * 4] = av;     // zero rows: no contribution
    }
    #pragma unroll
    for (int u = 0; u < 8; ++u) {
      int v = t + 256 * u;
      int row = v >> 6, col = v & 63;
      int gr = base + row; if (gr >= s1) gr = s1 - 1;   // in-bounds; a=0 anyway
      *(float4*)&xs[row * 260 + col * 4] =
          *(const float4*)&x[(size_t)gr * 256 + col * 4];
    }
    __syncthreads();
    #pragma unroll 4
    for (int r = 0; r < 32; ++r) {
      float4 a0 = *(const float4*)&as_[r * 68 + cg * 8];
      float4 a1 = *(const float4*)&as_[r * 68 + cg * 8 + 4];
      float4 x0 = *(const float4*)&xs[r * 260 + dg * 8];
      float4 x1 = *(const float4*)&xs[r * 260 + dg * 8 + 4];
      float ar[8] = {a0.x, a0.y, a0.z, a0.w, a1.x, a1.y, a1.z, a1.w};
      float xr[8] = {x0.x, x0.y, x0.z, x0.w, x1.x, x1.y, x1.z, x1.w};
      #pragma unroll
      for (int i = 0; i < 8; ++i)
        #pragma unroll
        for (int j = 0; j < 8; ++j) acc[i][j] += ar[i] * xr[j];
    }
    if (t < 64) {                      // asum column-sum
      #pragma unroll 8
      for (int r = 0; r < 32; ++r) asv += as_[r * 68 + t];
    }
    __syncthreads();
  }

  if (use_atomic) {
    float* g = Gdst + (size_t)b * 16384;
    #pragma unroll
    for (int i = 0; i < 8; ++i)
      #pragma unroll
      for (int j = 0; j < 8; ++j)
        atomicAdd(&g[(cg * 8 + i) * 256 + dg * 8 + j], acc[i][j]);
  } else {
    float* g = Gdst + ((size_t)blockIdx.x * 64 + b) * 16384;
    #pragma unroll
    for (int i = 0; i < 8; ++i) {
      *(float4*)&g[(cg * 8 + i) * 256 + dg * 8] =
          make_float4(acc[i][0], acc[i][1], acc[i][2], acc[i][3]);
      *(float4*)&g[(cg * 8 + i) * 256 + dg * 8 + 4] =
          make_float4(acc[i][4], acc[i][5], acc[i][6], acc[i][7]);
    }
  }
  if (t < 64) atomicAdd(&asum[b * 64 + t], asv);
}

// ---------------- finalize: out = relu(qo + (sum_p Gp)@Wf^T + asum*bvo + b) --

__global__ __launch_bounds__(256) void k_final(const float* __restrict__ Gp,
    int npart, const float* __restrict__ Wf, const float* __restrict__ qo,
    const float* __restrict__ asum, const float* __restrict__ bvo,
    const float* __restrict__ WO_b, float* __restrict__ out)
{
  __shared__ float gs[64 * 68];
  __shared__ float wfs[64 * 68];
  const int t = threadIdx.x;
  const int b = blockIdx.x >> 2;
  const int is = (blockIdx.x & 3) * 64;
  const int tx = t & 15, ty = t >> 4;
  const int sr = t >> 4, sq = t & 15;

  float acc[4][4];
  #pragma unroll
  for (int j = 0; j < 4; ++j)
    #pragma unroll
    for (int u = 0; u < 4; ++u) acc[j][u] = 0.f;

  for (int kc = 0; kc < 4; ++kc) {
    const int k0 = kc * 64;
    #pragma unroll
    for (int u = 0; u < 4; ++u) {
      int row = sr + 16 * u;
      float4 g = make_float4(0.f, 0.f, 0.f, 0.f);
      for (int p = 0; p < npart; ++p) {
        float4 gv = *(const float4*)&Gp[((size_t)p * 64 + b) * 16384
                                        + row * 256 + k0 + sq * 4];
        g.x += gv.x; g.y += gv.y; g.z += gv.z; g.w += gv.w;
      }
      *(float4*)&gs[row * 68 + sq * 4] = g;
      *(float4*)&wfs[row * 68 + sq * 4] =
          *(const float4*)&Wf[(size_t)(is + row) * 256 + k0 + sq * 4];
    }
    __syncthreads();
    #pragma unroll
    for (int k4 = 0; k4 < 16; ++k4) {
      float4 gr[4], wr[4];
      #pragma unroll
      for (int j = 0; j < 4; ++j) gr[j] = *(const float4*)&gs[(ty + 16 * j) * 68 + k4 * 4];
      #pragma unroll
      for (int u = 0; u < 4; ++u) wr[u] = *(const float4*)&wfs[(tx + 16 * u) * 68 + k4 * 4];
      #pragma unroll
      for (int j = 0; j < 4; ++j)
        #pragma unroll
        for (int u = 0; u < 4; ++u)
          acc[j][u] += gr[j].x * wr[u].x + gr[j].y * wr[u].y
                     + gr[j].z * wr[u].z + gr[j].w * wr[u].w;
    }
    __syncthreads();
  }

  #pragma unroll
  for (int j = 0; j < 4; ++j)
    #pragma unroll
    for (int u = 0; u < 4; ++u) {
      int c = ty + 16 * j, i = is + tx + 16 * u;
      float v = acc[j][u] + qo[c * 256 + i] + asum[b * 64 + c] * bvo[i] + WO_b[i];
      out[(size_t)b * 16384 + c * 256 + i] = fmaxf(v, 0.f);
    }
}

// ---------------- launch ----------------

extern "C" void kernel_launch(void* const* d_in, const int* in_sizes, int n_in,
                              void* d_out, int out_size, void* d_ws, size_t ws_size,
                              hipStream_t stream) {
  const float* x    = (const float*)d_in[0];
  const int*   batch= (const int*)d_in[1];
  const float* Qp   = (const float*)d_in[2];
  const float* WQ_w = (const float*)d_in[3];
  const float* WQ_b = (const float*)d_in[4];
  const float* WK_w = (const float*)d_in[5];
  const float* WK_b = (const float*)d_in[6];
  const float* WV_w = (const float*)d_in[7];
  const float* WV_b = (const float*)d_in[8];
  const float* WO_w = (const float*)d_in[9];
  const float* WO_b = (const float*)d_in[10];

  float* ws   = (float*)d_ws;
  float* QW   = ws + OFF_QW;
  float* QO   = ws + OFF_QO;
  float* Wf   = ws + OFF_WF;
  float* qb   = ws + OFF_QB;
  float* bvo  = ws + OFF_BVO;
  int*   starts = (int*)(ws + OFF_STARTS);
  float* asum = ws + OFF_ASUM;
  float* A    = ws + OFF_A;
  float* Gp   = ws + OFF_G;

  float* out     = (float*)d_out;                 // [64][64][256]
  float* out_arg = out + 64 * 64 * 256;           // [64][4096]
  float* out_msk = out_arg + 64 * MAXL;           // [64][4096]

  // G partials: 4 slabs (grid = 256 blocks) if ws allows, else atomic fallback
  size_t ws_f = ws_size / 4;
  size_t avail = ws_f > OFF_G ? ws_f - OFF_G : 0;
  size_t cap = avail / (64 * 16384);
  int npart, use_atomic;
  if (cap >= 4) { npart = 4; use_atomic = 0; }
  else          { npart = 1; use_atomic = 1; }
  int nchunk = use_atomic ? 16 : npart;

  hipMemsetAsync(asum, 0, 64 * 64 * sizeof(float), stream);
  hipMemsetAsync(out_arg, 0, (size_t)2 * 64 * MAXL * sizeof(float), stream);
  if (use_atomic) hipMemsetAsync(Gp, 0, (size_t)64 * 16384 * sizeof(float), stream);

  k_setup<<<321, 256, 0, stream>>>(Qp, WQ_w, WQ_b, WK_w, WK_b, WV_w, WV_b,
                                   WO_w, batch, QW, QO, qb, Wf, bvo, starts);
  k_scores<<<N_NODES / 64, 256, 0, stream>>>(x, batch, QW, qb, starts,
                                             A, out_arg, out_msk);
  k_gacc<<<dim3(nchunk, 64), 256, 0, stream>>>(x, A, starts, Gp, asum, use_atomic);
  k_final<<<64 * 4, 256, 0, stream>>>(Gp, npart, Wf, QO, asum, bvo, WO_b, out);
}

// Round 4
// 484.892 us; speedup vs baseline: 1.2115x; 1.2115x over previous
//
#include <hip/hip_runtime.h>

#define N_NODES 131072
#define MAXL 4096
#define NP 8

typedef __attribute__((ext_vector_type(8))) short bf16x8;
typedef __attribute__((ext_vector_type(4))) float f32x4;

// ws float offsets
#define OFF_QW     0u          // 64*256   folded (Q@WK)/16
#define OFF_QO     16384u      // 64*256   Q@WO^T
#define OFF_WF     32768u      // 256*256  WO@WV
#define OFF_QB     98304u      // 64
#define OFF_BVO    98368u      // 256
#define OFF_STARTS 98624u      // 65 ints (padded)
#define OFF_ASUM   98752u      // 64*64
#define OFF_Q      102848u     // 64*256
#define OFF_WQT    119232u     // 256*256
#define OFF_WOT    184768u     // 256*256
#define OFF_GP     250304u     // 8 * 64 * 16384  (end = 8638912 floats = 34.6 MB)

__device__ __forceinline__ unsigned short f2bf(float f) {
  union { float f; unsigned int u; } v; v.f = f;
  unsigned int u = v.u + 0x7FFFu + ((v.u >> 16) & 1u);  // RNE
  return (unsigned short)(u >> 16);
}

// ---------------- setup ----------------

// transpose WQ_w (z=0) and WO_w (z=1) into WQT / WOT
__global__ __launch_bounds__(256) void k_tr(const float* __restrict__ WQ_w,
    const float* __restrict__ WO_w, float* __restrict__ WQT, float* __restrict__ WOT)
{
  __shared__ float tile[32][33];
  const float* src = blockIdx.z ? WO_w : WQ_w;
  float* dst = blockIdx.z ? WOT : WQT;
  const int bx = blockIdx.x * 32, by = blockIdx.y * 32;
  const int tx = threadIdx.x & 31, ty = threadIdx.x >> 5;
  #pragma unroll
  for (int i = 0; i < 4; ++i)
    tile[ty + 8 * i][tx] = src[(size_t)(by + ty + 8 * i) * 256 + bx + tx];
  __syncthreads();
  #pragma unroll
  for (int i = 0; i < 4; ++i)
    dst[(size_t)(bx + ty + 8 * i) * 256 + by + tx] = tile[tx][ty + 8 * i];
}

// Q[c][d] = sum_k Qp[c][k] * WQT[k][d] + WQ_b[d]   (Qp scalar, WQT coalesced)
__global__ __launch_bounds__(256) void k_q(const float* __restrict__ Qp,
    const float* __restrict__ WQT, const float* __restrict__ WQ_b,
    float* __restrict__ Q)
{
  const int c = blockIdx.x, d = threadIdx.x;
  float acc = WQ_b[d];
  for (int k = 0; k < 256; ++k)
    acc += Qp[c * 256 + k] * WQT[k * 256 + d];
  Q[c * 256 + d] = acc;
}

// QW = (Q@WK)/16 (exact, fp64 acc), QO = Q@WO^T, qb = (Q@WK_b)/16
__global__ __launch_bounds__(256) void k_fold(const float* __restrict__ Q,
    const float* __restrict__ WK_w, const float* __restrict__ WK_b,
    const float* __restrict__ WOT,
    float* __restrict__ QW, float* __restrict__ QO, float* __restrict__ qb)
{
  __shared__ float Qrow[256];
  const int c = blockIdx.x, d = threadIdx.x;
  Qrow[d] = Q[c * 256 + d];
  __syncthreads();
  double aqw = 0.0;
  float aqo = 0.f;
  for (int j = 0; j < 256; ++j) {
    float qcj = Qrow[j];
    aqw += (double)qcj * (double)WK_w[j * 256 + d];   // coalesced
    aqo += qcj * WOT[j * 256 + d];                    // coalesced
  }
  QW[c * 256 + d] = (float)(aqw * 0.0625);
  QO[c * 256 + d] = aqo;
  if (d == 0) {
    double s = 0.0;
    for (int j = 0; j < 256; ++j) s += (double)Qrow[j] * (double)WK_b[j];
    qb[c] = (float)(s * 0.0625);
  }
}

__global__ __launch_bounds__(256) void k_wf(const float* __restrict__ WO_w,
    const float* __restrict__ WV_w, const float* __restrict__ WV_b,
    float* __restrict__ Wf, float* __restrict__ bvo)
{
  const int i = blockIdx.x, d = threadIdx.x;
  float acc = 0.f;
  for (int j = 0; j < 256; ++j)
    acc += WO_w[i * 256 + j] * WV_w[j * 256 + d];  // WO scalar, WV coalesced
  Wf[i * 256 + d] = acc;
  if (d == 0) {
    float s = 0.f;
    for (int j = 0; j < 256; ++j) s += WV_b[j] * WO_w[i * 256 + j];
    bvo[i] = s;
  }
}

__global__ void k_starts(const int* __restrict__ batch, int* __restrict__ starts)
{
  int t = threadIdx.x;
  if (t > 64) return;
  if (t == 0) { starts[0] = 0; return; }
  if (t == 64) { starts[64] = N_NODES; return; }
  int lo = 0, hi = N_NODES;
  while (lo < hi) {
    int mid = (lo + hi) >> 1;
    if (batch[mid] < t) lo = mid + 1; else hi = mid;
  }
  starts[t] = lo;
}

// ---------------- fused: scores + softmax + argmax/mask + G (MFMA) ----------
// grid (NP, 64 graphs), 256 threads. Chunk = 32 nodes.
// scores: thread = (cluster c=t&63, node-group ng=t>>6); x via LDS broadcast,
// q rows via global (L1-resident, shared by all 4 waves).
// G: per-wave 16-cluster tile, bf16 MFMA 16x16x32 over 16 d-tiles, acc persists.

__global__ __launch_bounds__(256, 2) void k_fused(
    const float* __restrict__ x, const int* __restrict__ starts,
    const float* __restrict__ qw, const float* __restrict__ qbv,
    float* __restrict__ Gp, float* __restrict__ asum,
    float* __restrict__ out_arg, float* __restrict__ out_msk)
{
  __shared__ float xs[32][256];                       // fp32 chunk, broadcast reads
  __shared__ float ss[32][65];                        // scores
  __shared__ float stats_m[32], stats_i[32];
  __shared__ __align__(16) unsigned short As[64][40]; // a bf16, [c][n], 80B rows
  __shared__ __align__(16) unsigned short XsT[256][40];// x bf16 transposed [d][n]

  const int t = threadIdx.x;
  const int p = blockIdx.x, b = blockIdx.y;
  const int s0 = starts[b], s1 = starts[b + 1];
  const int c = t & 63;         // cluster
  const int ng = t >> 6;        // wave id / node group
  const int lane = t & 63;

  f32x4 gacc[16];
  #pragma unroll
  for (int i = 0; i < 16; ++i) gacc[i] = (f32x4){0.f, 0.f, 0.f, 0.f};

  const float qbc = qbv[c];
  const float* qp = qw + (size_t)c * 256;
  float asv = 0.f;

  for (int base = s0 + p * 32; base < s1; base += NP * 32) {
    // ---- stage x chunk (coalesced 1KB/wave-row), fp32 -> LDS
    {
      int r = ng;
      #pragma unroll
      for (int i = 0; i < 8; ++i, r += 4) {
        int gr = base + r; if (gr >= s1) gr = s1 - 1;
        float4 v = *(const float4*)&x[(size_t)gr * 256 + lane * 4];
        *(float4*)&xs[r][lane * 4] = v;
      }
    }
    __syncthreads();
    // ---- XsT fill: thread d=t packs its column as bf16 [d][n]
    {
      const int d = t;
      #pragma unroll
      for (int g = 0; g < 8; ++g) {
        ushort4 pk;
        pk.x = f2bf(xs[g * 4 + 0][d]);
        pk.y = f2bf(xs[g * 4 + 1][d]);
        pk.z = f2bf(xs[g * 4 + 2][d]);
        pk.w = f2bf(xs[g * 4 + 3][d]);
        *(ushort4*)&XsT[d][g * 4] = pk;
      }
    }
    // ---- scores: acc[8] over nodes ng*8..+8, exact fp32
    float acc[8];
    #pragma unroll
    for (int i = 0; i < 8; ++i) acc[i] = 0.f;
    #pragma unroll 4
    for (int k4 = 0; k4 < 64; ++k4) {
      float4 qv = *(const float4*)&qp[k4 * 4];
      #pragma unroll
      for (int n = 0; n < 8; ++n) {
        float4 xv = *(const float4*)&xs[ng * 8 + n][k4 * 4];  // wave-broadcast
        acc[n] += qv.x * xv.x + qv.y * xv.y + qv.z * xv.z + qv.w * xv.w;
      }
    }
    #pragma unroll
    for (int n = 0; n < 8; ++n) ss[ng * 8 + n][c] = acc[n] + qbc;
    __syncthreads();
    // ---- softmax stats + argmax: 8 threads/node (oct split + shfl reduce)
    {
      const int nn = t >> 3, oct = t & 7;
      float v8[8];
      #pragma unroll
      for (int u = 0; u < 8; ++u) v8[u] = ss[nn][oct * 8 + u];
      float m = v8[0]; int am = oct * 8;
      #pragma unroll
      for (int u = 1; u < 8; ++u)
        if (v8[u] > m) { m = v8[u]; am = oct * 8 + u; }   // strict >: first max
      #pragma unroll
      for (int d = 1; d < 8; d <<= 1) {
        float mo = __shfl_xor(m, d);
        int ao = __shfl_xor(am, d);
        if (mo > m || (mo == m && ao < am)) { m = mo; am = ao; }
      }
      float s = 0.f;
      #pragma unroll
      for (int u = 0; u < 8; ++u) s += __expf(v8[u] - m);
      #pragma unroll
      for (int d = 1; d < 8; d <<= 1) s += __shfl_xor(s, d);
      if (oct == 0) {
        stats_m[nn] = m;
        stats_i[nn] = 1.f / s;
        int n = base + nn;
        if (n < s1) {
          int pos = n - s0;
          out_arg[(size_t)b * MAXL + pos] = (float)am;
          out_msk[(size_t)b * MAXL + pos] = 1.0f;
        }
      }
    }
    __syncthreads();
    // ---- a-values -> As (bf16) + asum (exact fp32)
    #pragma unroll
    for (int n = 0; n < 8; ++n) {
      const int nn = ng * 8 + n;
      bool valid = (base + nn) < s1;
      float a = valid ? __expf(acc[n] + qbc - stats_m[nn]) * stats_i[nn] : 0.f;
      asv += a;
      As[c][nn] = f2bf(a);
    }
    __syncthreads();
    // ---- G MFMA: wave ng owns clusters 16ng..16ng+16
    {
      const int q = lane >> 4, mm = lane & 15;
      bf16x8 afrag = *(const bf16x8*)&As[16 * ng + mm][q * 8];
      #pragma unroll
      for (int dt = 0; dt < 16; ++dt) {
        bf16x8 bfrag = *(const bf16x8*)&XsT[16 * dt + mm][q * 8];
        gacc[dt] = __builtin_amdgcn_mfma_f32_16x16x32_bf16(afrag, bfrag, gacc[dt], 0, 0, 0);
      }
    }
    __syncthreads();
  }

  // ---- epilogue: store G slab (D layout: row=4*(lane>>4)+r, col=lane&15)
  {
    float* g = Gp + ((size_t)p * 64 + b) * 16384;
    const int q = lane >> 4, mm = lane & 15;
    #pragma unroll
    for (int dt = 0; dt < 16; ++dt)
      #pragma unroll
      for (int r = 0; r < 4; ++r)
        g[(size_t)(16 * ng + q * 4 + r) * 256 + 16 * dt + mm] = gacc[dt][r];
  }
  atomicAdd(&asum[b * 64 + c], asv);
}

// ---------------- finalize: out = relu(qo + (sum_p Gp)@Wf^T + asum*bvo + b) --

__global__ __launch_bounds__(256) void k_final(const float* __restrict__ Gp,
    int npart, const float* __restrict__ Wf, const float* __restrict__ qo,
    const float* __restrict__ asum, const float* __restrict__ bvo,
    const float* __restrict__ WO_b, float* __restrict__ out)
{
  __shared__ float gs[64 * 68];
  __shared__ float wfs[64 * 68];
  const int t = threadIdx.x;
  const int b = blockIdx.x >> 2;
  const int is = (blockIdx.x & 3) * 64;
  const int tx = t & 15, ty = t >> 4;
  const int sr = t >> 4, sq = t & 15;

  float acc[4][4];
  #pragma unroll
  for (int j = 0; j < 4; ++j)
    #pragma unroll
    for (int u = 0; u < 4; ++u) acc[j][u] = 0.f;

  for (int kc = 0; kc < 4; ++kc) {
    const int k0 = kc * 64;
    #pragma unroll
    for (int u = 0; u < 4; ++u) {
      int row = sr + 16 * u;
      float4 g = make_float4(0.f, 0.f, 0.f, 0.f);
      for (int p = 0; p < npart; ++p) {
        float4 gv = *(const float4*)&Gp[((size_t)p * 64 + b) * 16384
                                        + row * 256 + k0 + sq * 4];
        g.x += gv.x; g.y += gv.y; g.z += gv.z; g.w += gv.w;
      }
      *(float4*)&gs[row * 68 + sq * 4] = g;
      *(float4*)&wfs[row * 68 + sq * 4] =
          *(const float4*)&Wf[(size_t)(is + row) * 256 + k0 + sq * 4];
    }
    __syncthreads();
    #pragma unroll
    for (int k4 = 0; k4 < 16; ++k4) {
      float4 gr[4], wr[4];
      #pragma unroll
      for (int j = 0; j < 4; ++j) gr[j] = *(const float4*)&gs[(ty + 16 * j) * 68 + k4 * 4];
      #pragma unroll
      for (int u = 0; u < 4; ++u) wr[u] = *(const float4*)&wfs[(tx + 16 * u) * 68 + k4 * 4];
      #pragma unroll
      for (int j = 0; j < 4; ++j)
        #pragma unroll
        for (int u = 0; u < 4; ++u)
          acc[j][u] += gr[j].x * wr[u].x + gr[j].y * wr[u].y
                     + gr[j].z * wr[u].z + gr[j].w * wr[u].w;
    }
    __syncthreads();
  }

  #pragma unroll
  for (int j = 0; j < 4; ++j)
    #pragma unroll
    for (int u = 0; u < 4; ++u) {
      int cc = ty + 16 * j, i = is + tx + 16 * u;
      float v = acc[j][u] + qo[cc * 256 + i] + asum[b * 64 + cc] * bvo[i] + WO_b[i];
      out[(size_t)b * 16384 + cc * 256 + i] = fmaxf(v, 0.f);
    }
}

// ---------------- launch ----------------

extern "C" void kernel_launch(void* const* d_in, const int* in_sizes, int n_in,
                              void* d_out, int out_size, void* d_ws, size_t ws_size,
                              hipStream_t stream) {
  const float* x    = (const float*)d_in[0];
  const int*   batch= (const int*)d_in[1];
  const float* Qp   = (const float*)d_in[2];
  const float* WQ_w = (const float*)d_in[3];
  const float* WQ_b = (const float*)d_in[4];
  const float* WK_w = (const float*)d_in[5];
  const float* WK_b = (const float*)d_in[6];
  const float* WV_w = (const float*)d_in[7];
  const float* WV_b = (const float*)d_in[8];
  const float* WO_w = (const float*)d_in[9];
  const float* WO_b = (const float*)d_in[10];

  float* ws   = (float*)d_ws;
  float* QW   = ws + OFF_QW;
  float* QO   = ws + OFF_QO;
  float* Wf   = ws + OFF_WF;
  float* qb   = ws + OFF_QB;
  float* bvo  = ws + OFF_BVO;
  int*   starts = (int*)(ws + OFF_STARTS);
  float* asum = ws + OFF_ASUM;
  float* Q    = ws + OFF_Q;
  float* WQT  = ws + OFF_WQT;
  float* WOT  = ws + OFF_WOT;
  float* Gp   = ws + OFF_GP;

  float* out     = (float*)d_out;                 // [64][64][256]
  float* out_arg = out + 64 * 64 * 256;           // [64][4096]
  float* out_msk = out_arg + 64 * MAXL;           // [64][4096]

  hipMemsetAsync(asum, 0, 64 * 64 * sizeof(float), stream);
  hipMemsetAsync(out_arg, 0, (size_t)2 * 64 * MAXL * sizeof(float), stream);

  k_tr<<<dim3(8, 8, 2), 256, 0, stream>>>(WQ_w, WO_w, WQT, WOT);
  k_wf<<<256, 256, 0, stream>>>(WO_w, WV_w, WV_b, Wf, bvo);
  k_starts<<<1, 128, 0, stream>>>(batch, starts);
  k_q<<<64, 256, 0, stream>>>(Qp, WQT, WQ_b, Q);
  k_fold<<<64, 256, 0, stream>>>(Q, WK_w, WK_b, WOT, QW, QO, qb);

  k_fused<<<dim3(NP, 64), 256, 0, stream>>>(x, starts, QW, qb, Gp, asum,
                                            out_arg, out_msk);
  k_final<<<64 * 4, 256, 0, stream>>>(Gp, NP, Wf, QO, asum, bvo, WO_b, out);
}

// Round 5
// 480.725 us; speedup vs baseline: 1.2220x; 1.0087x over previous
//
#include <hip/hip_runtime.h>

#define N_NODES 131072
#define MAXL 4096
#define NP 8

typedef __attribute__((ext_vector_type(8))) short bf16x8;
typedef __attribute__((ext_vector_type(4))) float f32x4;

// ws float offsets
#define OFF_QW     0u          // 64*256   folded (Q@WK)/16
#define OFF_QO     16384u      // 64*256   Q@WO^T
#define OFF_WF     32768u      // 256*256  WO@WV
#define OFF_QB     98304u      // 64
#define OFF_BVO    98368u      // 256
#define OFF_STARTS 98624u      // 65 ints (padded)
#define OFF_ASUM   98752u      // 64*64
#define OFF_Q      102848u     // 64*256
#define OFF_WQT    119232u     // 256*256
#define OFF_WOT    184768u     // 256*256
#define OFF_GP     250304u     // 8 * 64 * 16384  (end = 8638912 floats = 34.6 MB)

__device__ __forceinline__ unsigned short f2bf(float f) {
  union { float f; unsigned int u; } v; v.f = f;
  unsigned int u = v.u + 0x7FFFu + ((v.u >> 16) & 1u);  // RNE
  return (unsigned short)(u >> 16);
}

// ---------------- setup ----------------

// transpose WQ_w (z=0) and WO_w (z=1) into WQT / WOT
__global__ __launch_bounds__(256) void k_tr(const float* __restrict__ WQ_w,
    const float* __restrict__ WO_w, float* __restrict__ WQT, float* __restrict__ WOT)
{
  __shared__ float tile[32][33];
  const float* src = blockIdx.z ? WO_w : WQ_w;
  float* dst = blockIdx.z ? WOT : WQT;
  const int bx = blockIdx.x * 32, by = blockIdx.y * 32;
  const int tx = threadIdx.x & 31, ty = threadIdx.x >> 5;
  #pragma unroll
  for (int i = 0; i < 4; ++i)
    tile[ty + 8 * i][tx] = src[(size_t)(by + ty + 8 * i) * 256 + bx + tx];
  __syncthreads();
  #pragma unroll
  for (int i = 0; i < 4; ++i)
    dst[(size_t)(bx + ty + 8 * i) * 256 + by + tx] = tile[tx][ty + 8 * i];
}

// Q[c][d] = sum_k Qp[c][k] * WQT[k][d] + WQ_b[d]   (Qp scalar, WQT coalesced)
__global__ __launch_bounds__(256) void k_q(const float* __restrict__ Qp,
    const float* __restrict__ WQT, const float* __restrict__ WQ_b,
    float* __restrict__ Q)
{
  const int c = blockIdx.x, d = threadIdx.x;
  float acc = WQ_b[d];
  for (int k = 0; k < 256; ++k)
    acc += Qp[c * 256 + k] * WQT[k * 256 + d];
  Q[c * 256 + d] = acc;
}

// QW = (Q@WK)/16 (exact, fp64 acc), QO = Q@WO^T, qb = (Q@WK_b)/16
__global__ __launch_bounds__(256) void k_fold(const float* __restrict__ Q,
    const float* __restrict__ WK_w, const float* __restrict__ WK_b,
    const float* __restrict__ WOT,
    float* __restrict__ QW, float* __restrict__ QO, float* __restrict__ qb)
{
  __shared__ float Qrow[256];
  const int c = blockIdx.x, d = threadIdx.x;
  Qrow[d] = Q[c * 256 + d];
  __syncthreads();
  double aqw = 0.0;
  float aqo = 0.f;
  for (int j = 0; j < 256; ++j) {
    float qcj = Qrow[j];
    aqw += (double)qcj * (double)WK_w[j * 256 + d];   // coalesced
    aqo += qcj * WOT[j * 256 + d];                    // coalesced
  }
  QW[c * 256 + d] = (float)(aqw * 0.0625);
  QO[c * 256 + d] = aqo;
  if (d == 0) {
    double s = 0.0;
    for (int j = 0; j < 256; ++j) s += (double)Qrow[j] * (double)WK_b[j];
    qb[c] = (float)(s * 0.0625);
  }
}

__global__ __launch_bounds__(256) void k_wf(const float* __restrict__ WO_w,
    const float* __restrict__ WV_w, const float* __restrict__ WV_b,
    float* __restrict__ Wf, float* __restrict__ bvo)
{
  const int i = blockIdx.x, d = threadIdx.x;
  float acc = 0.f;
  for (int j = 0; j < 256; ++j)
    acc += WO_w[i * 256 + j] * WV_w[j * 256 + d];  // WO scalar, WV coalesced
  Wf[i * 256 + d] = acc;
  if (d == 0) {
    float s = 0.f;
    for (int j = 0; j < 256; ++j) s += WV_b[j] * WO_w[i * 256 + j];
    bvo[i] = s;
  }
}

__global__ void k_starts(const int* __restrict__ batch, int* __restrict__ starts)
{
  int t = threadIdx.x;
  if (t > 64) return;
  if (t == 0) { starts[0] = 0; return; }
  if (t == 64) { starts[64] = N_NODES; return; }
  int lo = 0, hi = N_NODES;
  while (lo < hi) {
    int mid = (lo + hi) >> 1;
    if (batch[mid] < t) lo = mid + 1; else hi = mid;
  }
  starts[t] = lo;
}

// ---------------- fused: scores + softmax + argmax/mask + G (MFMA) ----------
// grid (NP, 64 graphs), 256 threads. Chunk = 32 nodes.
// scores: thread = (cluster c=t&63, node-group ng=t>>6); x via LDS broadcast,
// q streamed through LDS in 64-k slices (coalesced staging -> kills the
// per-lane 64-line L1 gather that bound round 4).
// G: per-wave 16-cluster tile, bf16 MFMA 16x16x32 over 16 d-tiles, acc persists.

__global__ __launch_bounds__(256, 2) void k_fused(
    const float* __restrict__ x, const int* __restrict__ starts,
    const float* __restrict__ qw, const float* __restrict__ qbv,
    float* __restrict__ Gp, float* __restrict__ asum,
    float* __restrict__ out_arg, float* __restrict__ out_msk)
{
  __shared__ float xs[32][256];                       // fp32 chunk, broadcast reads
  __shared__ float qs[64][68];                        // q k-slice [c][64k], pad 68
  __shared__ float ss[32][65];                        // scores
  __shared__ float stats_m[32], stats_i[32];
  __shared__ __align__(16) unsigned short As[64][40]; // a bf16, [c][n]
  __shared__ __align__(16) unsigned short XsT[256][32];// x bf16 transposed [d][n]

  const int t = threadIdx.x;
  const int p = blockIdx.x, b = blockIdx.y;
  const int s0 = starts[b], s1 = starts[b + 1];
  const int c = t & 63;         // cluster
  const int ng = t >> 6;        // wave id / node group
  const int lane = t & 63;

  f32x4 gacc[16];
  #pragma unroll
  for (int i = 0; i < 16; ++i) gacc[i] = (f32x4){0.f, 0.f, 0.f, 0.f};

  const float qbc = qbv[c];
  // qs staging map: thread covers row cs = t>>2, 16 consecutive k at (t&3)*16
  const int cs = t >> 2, kq = (t & 3) * 16;
  float asv = 0.f;

  for (int base = s0 + p * 32; base < s1; base += NP * 32) {
    // ---- stage x chunk (coalesced 1KB/wave-row), fp32 -> LDS
    {
      int r = ng;
      #pragma unroll
      for (int i = 0; i < 8; ++i, r += 4) {
        int gr = base + r; if (gr >= s1) gr = s1 - 1;
        float4 v = *(const float4*)&x[(size_t)gr * 256 + lane * 4];
        *(float4*)&xs[r][lane * 4] = v;
      }
    }
    __syncthreads();
    // ---- XsT fill: thread d=t packs its column as bf16 [d][n]
    {
      const int d = t;
      #pragma unroll
      for (int g = 0; g < 8; ++g) {
        ushort4 pk;
        pk.x = f2bf(xs[g * 4 + 0][d]);
        pk.y = f2bf(xs[g * 4 + 1][d]);
        pk.z = f2bf(xs[g * 4 + 2][d]);
        pk.w = f2bf(xs[g * 4 + 3][d]);
        *(ushort4*)&XsT[d][g * 4] = pk;
      }
    }
    // ---- scores: acc[8] over nodes ng*8..+8, exact fp32; q via LDS slices
    float acc[8];
    #pragma unroll
    for (int i = 0; i < 8; ++i) acc[i] = 0.f;
    #pragma unroll 1
    for (int s = 0; s < 4; ++s) {
      // stage q slice [64c][64k] -- coalesced 256B runs per c-row
      {
        const float* qg = qw + (size_t)cs * 256 + s * 64 + kq;
        float4 v0 = *(const float4*)&qg[0];
        float4 v1 = *(const float4*)&qg[4];
        float4 v2 = *(const float4*)&qg[8];
        float4 v3 = *(const float4*)&qg[12];
        *(float4*)&qs[cs][kq + 0]  = v0;
        *(float4*)&qs[cs][kq + 4]  = v1;
        *(float4*)&qs[cs][kq + 8]  = v2;
        *(float4*)&qs[cs][kq + 12] = v3;
      }
      __syncthreads();
      #pragma unroll 4
      for (int k4 = 0; k4 < 16; ++k4) {
        float4 qv = *(const float4*)&qs[c][k4 * 4];
        #pragma unroll
        for (int n = 0; n < 8; ++n) {
          float4 xv = *(const float4*)&xs[ng * 8 + n][s * 64 + k4 * 4];  // broadcast
          acc[n] += qv.x * xv.x + qv.y * xv.y + qv.z * xv.z + qv.w * xv.w;
        }
      }
      __syncthreads();
    }
    #pragma unroll
    for (int n = 0; n < 8; ++n) ss[ng * 8 + n][c] = acc[n] + qbc;
    __syncthreads();
    // ---- softmax stats + argmax: 8 threads/node (oct split + shfl reduce)
    {
      const int nn = t >> 3, oct = t & 7;
      float v8[8];
      #pragma unroll
      for (int u = 0; u < 8; ++u) v8[u] = ss[nn][oct * 8 + u];
      float m = v8[0]; int am = oct * 8;
      #pragma unroll
      for (int u = 1; u < 8; ++u)
        if (v8[u] > m) { m = v8[u]; am = oct * 8 + u; }   // strict >: first max
      #pragma unroll
      for (int d = 1; d < 8; d <<= 1) {
        float mo = __shfl_xor(m, d);
        int ao = __shfl_xor(am, d);
        if (mo > m || (mo == m && ao < am)) { m = mo; am = ao; }
      }
      float s = 0.f;
      #pragma unroll
      for (int u = 0; u < 8; ++u) s += __expf(v8[u] - m);
      #pragma unroll
      for (int d = 1; d < 8; d <<= 1) s += __shfl_xor(s, d);
      if (oct == 0) {
        stats_m[nn] = m;
        stats_i[nn] = 1.f / s;
        int n = base + nn;
        if (n < s1) {
          int pos = n - s0;
          out_arg[(size_t)b * MAXL + pos] = (float)am;
          out_msk[(size_t)b * MAXL + pos] = 1.0f;
        }
      }
    }
    __syncthreads();
    // ---- a-values -> As (bf16) + asum (exact fp32)
    #pragma unroll
    for (int n = 0; n < 8; ++n) {
      const int nn = ng * 8 + n;
      bool valid = (base + nn) < s1;
      float a = valid ? __expf(acc[n] + qbc - stats_m[nn]) * stats_i[nn] : 0.f;
      asv += a;
      As[c][nn] = f2bf(a);
    }
    __syncthreads();
    // ---- G MFMA: wave ng owns clusters 16ng..16ng+16
    {
      const int q = lane >> 4, mm = lane & 15;
      bf16x8 afrag = *(const bf16x8*)&As[16 * ng + mm][q * 8];
      #pragma unroll
      for (int dt = 0; dt < 16; ++dt) {
        bf16x8 bfrag = *(const bf16x8*)&XsT[16 * dt + mm][q * 8];
        gacc[dt] = __builtin_amdgcn_mfma_f32_16x16x32_bf16(afrag, bfrag, gacc[dt], 0, 0, 0);
      }
    }
    __syncthreads();
  }

  // ---- epilogue: store G slab (D layout: row=4*(lane>>4)+r, col=lane&15)
  {
    float* g = Gp + ((size_t)p * 64 + b) * 16384;
    const int q = lane >> 4, mm = lane & 15;
    #pragma unroll
    for (int dt = 0; dt < 16; ++dt)
      #pragma unroll
      for (int r = 0; r < 4; ++r)
        g[(size_t)(16 * ng + q * 4 + r) * 256 + 16 * dt + mm] = gacc[dt][r];
  }
  atomicAdd(&asum[b * 64 + c], asv);
}

// ---------------- finalize: out = relu(qo + (sum_p Gp)@Wf^T + asum*bvo + b) --

__global__ __launch_bounds__(256) void k_final(const float* __restrict__ Gp,
    int npart, const float* __restrict__ Wf, const float* __restrict__ qo,
    const float* __restrict__ asum, const float* __restrict__ bvo,
    const float* __restrict__ WO_b, float* __restrict__ out)
{
  __shared__ float gs[64 * 68];
  __shared__ float wfs[64 * 68];
  const int t = threadIdx.x;
  const int b = blockIdx.x >> 2;
  const int is = (blockIdx.x & 3) * 64;
  const int tx = t & 15, ty = t >> 4;
  const int sr = t >> 4, sq = t & 15;

  float acc[4][4];
  #pragma unroll
  for (int j = 0; j < 4; ++j)
    #pragma unroll
    for (int u = 0; u < 4; ++u) acc[j][u] = 0.f;

  for (int kc = 0; kc < 4; ++kc) {
    const int k0 = kc * 64;
    #pragma unroll
    for (int u = 0; u < 4; ++u) {
      int row = sr + 16 * u;
      float4 g = make_float4(0.f, 0.f, 0.f, 0.f);
      for (int p = 0; p < npart; ++p) {
        float4 gv = *(const float4*)&Gp[((size_t)p * 64 + b) * 16384
                                        + row * 256 + k0 + sq * 4];
        g.x += gv.x; g.y += gv.y; g.z += gv.z; g.w += gv.w;
      }
      *(float4*)&gs[row * 68 + sq * 4] = g;
      *(float4*)&wfs[row * 68 + sq * 4] =
          *(const float4*)&Wf[(size_t)(is + row) * 256 + k0 + sq * 4];
    }
    __syncthreads();
    #pragma unroll
    for (int k4 = 0; k4 < 16; ++k4) {
      float4 gr[4], wr[4];
      #pragma unroll
      for (int j = 0; j < 4; ++j) gr[j] = *(const float4*)&gs[(ty + 16 * j) * 68 + k4 * 4];
      #pragma unroll
      for (int u = 0; u < 4; ++u) wr[u] = *(const float4*)&wfs[(tx + 16 * u) * 68 + k4 * 4];
      #pragma unroll
      for (int j = 0; j < 4; ++j)
        #pragma unroll
        for (int u = 0; u < 4; ++u)
          acc[j][u] += gr[j].x * wr[u].x + gr[j].y * wr[u].y
                     + gr[j].z * wr[u].z + gr[j].w * wr[u].w;
    }
    __syncthreads();
  }

  #pragma unroll
  for (int j = 0; j < 4; ++j)
    #pragma unroll
    for (int u = 0; u < 4; ++u) {
      int cc = ty + 16 * j, i = is + tx + 16 * u;
      float v = acc[j][u] + qo[cc * 256 + i] + asum[b * 64 + cc] * bvo[i] + WO_b[i];
      out[(size_t)b * 16384 + cc * 256 + i] = fmaxf(v, 0.f);
    }
}

// ---------------- launch ----------------

extern "C" void kernel_launch(void* const* d_in, const int* in_sizes, int n_in,
                              void* d_out, int out_size, void* d_ws, size_t ws_size,
                              hipStream_t stream) {
  const float* x    = (const float*)d_in[0];
  const int*   batch= (const int*)d_in[1];
  const float* Qp   = (const float*)d_in[2];
  const float* WQ_w = (const float*)d_in[3];
  const float* WQ_b = (const float*)d_in[4];
  const float* WK_w = (const float*)d_in[5];
  const float* WK_b = (const float*)d_in[6];
  const float* WV_w = (const float*)d_in[7];
  const float* WV_b = (const float*)d_in[8];
  const float* WO_w = (const float*)d_in[9];
  const float* WO_b = (const float*)d_in[10];

  float* ws   = (float*)d_ws;
  float* QW   = ws + OFF_QW;
  float* QO   = ws + OFF_QO;
  float* Wf   = ws + OFF_WF;
  float* qb   = ws + OFF_QB;
  float* bvo  = ws + OFF_BVO;
  int*   starts = (int*)(ws + OFF_STARTS);
  float* asum = ws + OFF_ASUM;
  float* Q    = ws + OFF_Q;
  float* WQT  = ws + OFF_WQT;
  float* WOT  = ws + OFF_WOT;
  float* Gp   = ws + OFF_GP;

  float* out     = (float*)d_out;                 // [64][64][256]
  float* out_arg = out + 64 * 64 * 256;           // [64][4096]
  float* out_msk = out_arg + 64 * MAXL;           // [64][4096]

  hipMemsetAsync(asum, 0, 64 * 64 * sizeof(float), stream);
  hipMemsetAsync(out_arg, 0, (size_t)2 * 64 * MAXL * sizeof(float), stream);

  k_tr<<<dim3(8, 8, 2), 256, 0, stream>>>(WQ_w, WO_w, WQT, WOT);
  k_wf<<<256, 256, 0, stream>>>(WO_w, WV_w, WV_b, Wf, bvo);
  k_starts<<<1, 128, 0, stream>>>(batch, starts);
  k_q<<<64, 256, 0, stream>>>(Qp, WQT, WQ_b, Q);
  k_fold<<<64, 256, 0, stream>>>(Q, WK_w, WK_b, WOT, QW, QO, qb);

  k_fused<<<dim3(NP, 64), 256, 0, stream>>>(x, starts, QW, qb, Gp, asum,
                                            out_arg, out_msk);
  k_final<<<64 * 4, 256, 0, stream>>>(Gp, NP, Wf, QO, asum, bvo, WO_b, out);
}